// Round 9
// baseline (760.788 us; speedup 1.0000x reference)
//
#include <hip/hip_runtime.h>
#include <math.h>

// Problem constants (match reference)
#define B_      4
#define L_      1024
#define D_INNC  8      // D_IN
#define DMODEL  512
#define DEPTH_  4
#define DINNER  1024
#define DSTATE  16
#define DCONV   4
#define DTRANK  32
#define MTOT    (B_*L_)   // 4096
#define CHUNKS  32
#define CLEN    32        // L_/CHUNKS
#define MROWS   8         // rows per mid-kernel block

typedef float f32x4 __attribute__((ext_vector_type(4)));
typedef short s16x8 __attribute__((ext_vector_type(8)));
typedef unsigned short u16;
typedef unsigned short u16x4v __attribute__((ext_vector_type(4)));

// fp32 -> bf16 round-to-nearest-even
__device__ __forceinline__ u16 f2bf(float v) {
    unsigned b = __float_as_uint(v);
    return (u16)((b + 0x7FFF + ((b >> 16) & 1)) >> 16);
}
__device__ __forceinline__ float bf2f(u16 h) {
    return __uint_as_float((unsigned)h << 16);
}

// ---------------------------------------------------------------------------
// h = x @ in_w^T + in_b  -> bf16 (4096 x 512, K=8)
__global__ __launch_bounds__(256) void in_proj_kernel(
    const float* __restrict__ x, const float* __restrict__ w,
    const float* __restrict__ bias, u16* __restrict__ hb)
{
    int idx = blockIdx.x * 256 + threadIdx.x;
    int m = idx / DMODEL, d = idx % DMODEL;
    const float* xr = x + m * D_INNC;
    const float* wr = w + d * D_INNC;
    float acc = bias[d];
#pragma unroll
    for (int k = 0; k < D_INNC; ++k) acc += xr[k] * wr[k];
    hb[idx] = f2bf(acc);
}

// ---------------------------------------------------------------------------
// fp32 -> bf16 array convert, 8 elems/thread.
__global__ __launch_bounds__(256) void wconv_kernel(
    const float* __restrict__ W, u16* __restrict__ Wb)
{
    int i = blockIdx.x * 256 + threadIdx.x;
    const float* src = W + (size_t)i * 8;
    float4 f0 = *(const float4*)src;
    float4 f1 = *(const float4*)(src + 4);
    float f[8] = {f0.x,f0.y,f0.z,f0.w,f1.x,f1.y,f1.z,f1.w};
    s16x8 hv;
#pragma unroll
    for (int e = 0; e < 8; ++e) hv[e] = (short)f2bf(f[e]);
    *(s16x8*)(Wb + (size_t)i * 8) = hv;
}

// ---------------------------------------------------------------------------
// bf16 MFMA NT GEMM: C[m,n] = sum_k A[m,k]*B[n,k].
// 256 thr = 4 waves (2x2); wave tile (BM/2)x(BN/2).
// MODE 1: xz epilogue — col<1024: bf16 xcb; col>=1024: silu -> bf16 szb.
// MODE 2: bf16 direct out to C0 (ldc).
template<int BM, int BN, int MODE>
__global__ __launch_bounds__(256, 2) void gemm_bf16(
    const u16* __restrict__ A, int lda,
    const u16* __restrict__ B, int ldb,
    void* __restrict__ C0, void* __restrict__ C1,
    int ldc, int K)
{
    constexpr int FM  = BM / 32;            // m-fragments per wave
    constexpr int FN  = BN / 32;            // n-fragments per wave
    constexpr int ACH = BM / 64;            // A 8-elem chunks per thread
    constexpr int BCH = BN / 64;            // B chunks per thread
    __shared__ __align__(16) u16 As[4*(BM+1)*8];
    __shared__ __align__(16) u16 Bs[4*(BN+1)*8];

    const int t    = threadIdx.x;
    const int lane = t & 63;
    const int w    = t >> 6;
    const int wm   = (w >> 1) * (BM / 2);
    const int wn   = (w & 1) * (BN / 2);
    const int quad = lane >> 4;
    const int l16  = lane & 15;
    const int m0   = blockIdx.y * BM;
    const int n0   = blockIdx.x * BN;

    f32x4 acc[FM][FN];
#pragma unroll
    for (int i = 0; i < FM; ++i)
#pragma unroll
        for (int j = 0; j < FN; ++j) acc[i][j] = (f32x4){0.f,0.f,0.f,0.f};

    s16x8 ra[ACH], rb[BCH];
#pragma unroll
    for (int c = 0; c < ACH; ++c) {
        int id = c*256 + t, row = id >> 2, kb = id & 3;
        ra[c] = *(const s16x8*)(A + (size_t)(m0 + row) * lda + kb*8);
    }
#pragma unroll
    for (int c = 0; c < BCH; ++c) {
        int id = c*256 + t, row = id >> 2, kb = id & 3;
        rb[c] = *(const s16x8*)(B + (size_t)(n0 + row) * ldb + kb*8);
    }

    for (int kk = 0; kk < K; kk += 32) {
        __syncthreads();
#pragma unroll
        for (int c = 0; c < ACH; ++c) {
            int id = c*256 + t, row = id >> 2, kb = id & 3;
            *(s16x8*)&As[(kb*(BM+1) + row) * 8] = ra[c];
        }
#pragma unroll
        for (int c = 0; c < BCH; ++c) {
            int id = c*256 + t, row = id >> 2, kb = id & 3;
            *(s16x8*)&Bs[(kb*(BN+1) + row) * 8] = rb[c];
        }
        __syncthreads();
        int kn = kk + 32;
        if (kn < K) {   // prefetch next K-slice, overlaps MFMA below
#pragma unroll
            for (int c = 0; c < ACH; ++c) {
                int id = c*256 + t, row = id >> 2, kb = id & 3;
                ra[c] = *(const s16x8*)(A + (size_t)(m0 + row) * lda + kn + kb*8);
            }
#pragma unroll
            for (int c = 0; c < BCH; ++c) {
                int id = c*256 + t, row = id >> 2, kb = id & 3;
                rb[c] = *(const s16x8*)(B + (size_t)(n0 + row) * ldb + kn + kb*8);
            }
        }
        s16x8 afr[FM], bfr[FN];
#pragma unroll
        for (int i = 0; i < FM; ++i)
            afr[i] = *(const s16x8*)&As[(quad*(BM+1) + wm + i*16 + l16) * 8];
#pragma unroll
        for (int j = 0; j < FN; ++j)
            bfr[j] = *(const s16x8*)&Bs[(quad*(BN+1) + wn + j*16 + l16) * 8];
#pragma unroll
        for (int i = 0; i < FM; ++i)
#pragma unroll
            for (int j = 0; j < FN; ++j)
                acc[i][j] = __builtin_amdgcn_mfma_f32_16x16x32_bf16(afr[i], bfr[j], acc[i][j], 0, 0, 0);
    }

    // epilogue: C/D layout col=lane&15, row=quad*4+reg
    if (MODE == 2) {
        u16* C = (u16*)C0;
#pragma unroll
        for (int i = 0; i < FM; ++i)
#pragma unroll
            for (int j = 0; j < FN; ++j) {
                int col = n0 + wn + j*16 + l16;
#pragma unroll
                for (int r = 0; r < 4; ++r) {
                    int row = m0 + wm + i*16 + quad*4 + r;
                    C[(size_t)row * ldc + col] = f2bf(acc[i][j][r]);
                }
            }
    } else {
        u16* xcb = (u16*)C0;
        u16* szb = (u16*)C1;
#pragma unroll
        for (int i = 0; i < FM; ++i)
#pragma unroll
            for (int j = 0; j < FN; ++j) {
                int col = n0 + wn + j*16 + l16;
                bool isz = col >= DINNER;
                int cc = col & (DINNER - 1);
                u16* dst = isz ? szb : xcb;
#pragma unroll
                for (int r = 0; r < 4; ++r) {
                    int row = m0 + wm + i*16 + quad*4 + r;
                    float v = acc[i][j][r];
                    if (isz) v = v / (1.f + __expf(-v));   // silu(z)
                    dst[(size_t)row * DINNER + cc] = f2bf(v);
                }
            }
    }
}

// ---------------------------------------------------------------------------
// Fused mid kernel: conv+silu -> u (global bf16 + LDS fp32), x-proj (B/C cols
// of xdbl + dt_lr in LDS), dt GEMM + softplus -> dtb. 8 m-rows per block.
__global__ __launch_bounds__(256) void mid_kernel(
    const u16* __restrict__ xcb, const float* __restrict__ cw,
    const float* __restrict__ cb, const float* __restrict__ Wxp,
    const float* __restrict__ Wdt, const float* __restrict__ bdt,
    u16* __restrict__ ub, float* __restrict__ xdbl, u16* __restrict__ dtb)
{
    __shared__ float smemA[8448];          // us[8][1024] -> wdt tile [256][33]
    __shared__ float Ws[64][65];
    __shared__ float al[MROWS][33];
    const int t  = threadIdx.x;
    const int m0 = blockIdx.x * MROWS;
    float* us = smemA;

    // ---- Phase A: depthwise conv (k=4) + bias + SiLU ----
#pragma unroll
    for (int cc = 0; cc < 4; ++cc) {
        int d = cc*256 + t;
        const float4 w4 = *(const float4*)&cw[d * 4];
        float xv[MROWS + 3];
#pragma unroll
        for (int i = 0; i < MROWS + 3; ++i) {
            int m = m0 - 3 + i; if (m < 0) m = 0;
            xv[i] = bf2f(xcb[(size_t)m * DINNER + d]);
        }
        float bias = cb[d];
#pragma unroll
        for (int r = 0; r < MROWS; ++r) {
            int l = (m0 + r) & (L_ - 1);
            float a = bias;
            if (l >= 3) a += xv[r]     * w4.x;
            if (l >= 2) a += xv[r + 1] * w4.y;
            if (l >= 1) a += xv[r + 2] * w4.z;
            a += xv[r + 3] * w4.w;
            float uu = a / (1.f + __expf(-a));
            us[r * 1024 + d] = uu;
            ub[(size_t)(m0 + r) * DINNER + d] = f2bf(uu);
        }
    }
    __syncthreads();

    // ---- Phase B: x-proj (8x64, K=1024) ----
    {
        const int n = t & 63, rr = t >> 6;
        float acc0 = 0.f, acc1 = 0.f;
        for (int k0 = 0; k0 < DINNER; k0 += 64) {
            __syncthreads();
            {   // stage W tile 64x64 coalesced
                int r = t >> 2, f = t & 3;
#pragma unroll
                for (int q = 0; q < 4; ++q) {
                    float4 v = *(const float4*)&Wxp[(size_t)r * DINNER + k0 + f*16 + q*4];
                    Ws[r][f*16+q*4+0] = v.x; Ws[r][f*16+q*4+1] = v.y;
                    Ws[r][f*16+q*4+2] = v.z; Ws[r][f*16+q*4+3] = v.w;
                }
            }
            __syncthreads();
#pragma unroll 8
            for (int kk = 0; kk < 64; ++kk) {
                float w = Ws[n][kk];
                acc0 += us[rr * 1024 + k0 + kk] * w;
                acc1 += us[(rr + 4) * 1024 + k0 + kk] * w;
            }
        }
        if (n >= 32) {
            xdbl[(size_t)(m0 + rr) * 64 + n]     = acc0;
            xdbl[(size_t)(m0 + rr + 4) * 64 + n] = acc1;
        } else {
            al[rr][n] = acc0; al[rr + 4][n] = acc1;
        }
    }
    __syncthreads();

    // ---- Phase C: dt = softplus(dt_lr @ Wdt^T + b_dt) ----
    float* wdt_s = smemA;                   // [256][33] padded
    for (int cc = 0; cc < 4; ++cc) {
        const int nbase = cc * 256;
        __syncthreads();
        {   // stage 256 Wdt rows coalesced, padded-row store
            const float4* src = (const float4*)(Wdt + (size_t)nbase * DTRANK);
#pragma unroll
            for (int e = 0; e < 8; ++e) {
                float4 v = src[e * 256 + t];
                int li = (e * 256 + t) * 4;
                int row = li >> 5, col = li & 31;
                wdt_s[row * 33 + col + 0] = v.x; wdt_s[row * 33 + col + 1] = v.y;
                wdt_s[row * 33 + col + 2] = v.z; wdt_s[row * 33 + col + 3] = v.w;
            }
        }
        __syncthreads();
        float bb = bdt[nbase + t];
        float acc[MROWS];
#pragma unroll
        for (int r = 0; r < MROWS; ++r) acc[r] = bb;
#pragma unroll
        for (int k = 0; k < DTRANK; ++k) {
            float w = wdt_s[t * 33 + k];
#pragma unroll
            for (int r = 0; r < MROWS; ++r) acc[r] += al[r][k] * w;
        }
#pragma unroll
        for (int r = 0; r < MROWS; ++r) {
            float v = acc[r];
            float sp = (v > 20.f) ? v : log1pf(expf(v));
            dtb[(size_t)(m0 + r) * DINNER + nbase + t] = f2bf(sp);
        }
    }
}

// ---------------------------------------------------------------------------
// Chunked scan pass 1 — one lane per (b,c,d), 16 states in VGPRs.
// hfinal stored bf16; dt-sums stored into dead cols 0..31 of xdbl.
__global__ __launch_bounds__(256) void scan1_kernel(
    const u16* __restrict__ ub, const float* xdbl,
    const u16* __restrict__ dtb, const float* __restrict__ A_log,
    u16* __restrict__ hfinal, float* dtsum_out)
{
    __shared__ float Bs[CLEN][16];
    const int blk  = blockIdx.x;              // b*128 + c*4 + dblk
    const int dblk = blk & 3;
    const int c    = (blk >> 2) & (CHUNKS - 1);
    const int b    = blk >> 7;
    const int d    = dblk * 256 + threadIdx.x;
    const int mbase = b * L_ + c * CLEN;

#pragma unroll
    for (int q = 0; q < 2; ++q) {
        int idx = q * 256 + threadIdx.x;
        int tt = idx >> 4, ss = idx & 15;
        Bs[tt][ss] = xdbl[(size_t)(mbase + tt) * 64 + 32 + ss];
    }
    float A[16];
    {
        float4 a4[4];
#pragma unroll
        for (int q = 0; q < 4; ++q) a4[q] = *(const float4*)&A_log[d * 16 + q * 4];
        const float* af = (const float*)a4;
#pragma unroll
        for (int s = 0; s < 16; ++s) A[s] = -__expf(af[s]);
    }
    __syncthreads();

    float h[16];
#pragma unroll
    for (int s = 0; s < 16; ++s) h[s] = 0.f;
    float dts = 0.f;

    for (int t0 = 0; t0 < CLEN; t0 += 8) {
        float dt8[8], u8[8];
#pragma unroll
        for (int j = 0; j < 8; ++j) {
            int m = mbase + t0 + j;
            dt8[j] = bf2f(dtb[(size_t)m * DINNER + d]);
            u8[j]  = bf2f(ub [(size_t)m * DINNER + d]);
        }
#pragma unroll
        for (int j = 0; j < 8; ++j) {
            float dtv = dt8[j], dtu = dtv * u8[j];
            dts += dtv;
            float Bt[16];
#pragma unroll
            for (int q = 0; q < 4; ++q)
                *(float4*)&Bt[q*4] = *(const float4*)&Bs[t0 + j][q*4];
#pragma unroll
            for (int s = 0; s < 16; ++s) {
                float dA = __expf(dtv * A[s]);
                h[s] = dA * h[s] + dtu * Bt[s];
            }
        }
    }
    size_t base = ((size_t)(b * CHUNKS + c) * DINNER + d) * 16;
    s16x8 p0, p1;
#pragma unroll
    for (int s = 0; s < 8; ++s) { p0[s] = (short)f2bf(h[s]); p1[s] = (short)f2bf(h[s+8]); }
    *(s16x8*)&hfinal[base]     = p0;
    *(s16x8*)&hfinal[base + 8] = p1;
    int i = (b * CHUNKS + c) * DINNER + d;
    dtsum_out[(i >> 5) * 64 + (i & 31)] = dts;
}

// Pass 2: sequential chunk fix-up (bf16 states, fp32 math).
__global__ __launch_bounds__(256) void scan2_kernel(
    u16* __restrict__ hfinal, const float* __restrict__ dtsum,
    const float* __restrict__ A_log)
{
    int t = blockIdx.x * 256 + threadIdx.x;   // 65536 = B_*DINNER*DSTATE
    int s = t & 15, d = (t >> 4) & (DINNER - 1), b = t >> 14;
    float As = -__expf(A_log[d * DSTATE + s]);
    float h = 0.f;
    for (int c0 = 0; c0 < CHUNKS; c0 += 8) {
        float hf8[8], dts8[8];
#pragma unroll
        for (int j = 0; j < 8; ++j) {
            int c = c0 + j;
            int i = (b * CHUNKS + c) * DINNER + d;
            dts8[j] = dtsum[(i >> 5) * 64 + (i & 31)];
            hf8[j]  = bf2f(hfinal[((size_t)i) * 16 + s]);
        }
#pragma unroll
        for (int j = 0; j < 8; ++j) {
            int c = c0 + j;
            size_t idx = ((size_t)((b * CHUNKS + c) * DINNER + d)) * 16 + s;
            hfinal[idx] = f2bf(h);
            h = __expf(As * dts8[j]) * h + hf8[j];
        }
    }
}

// Pass 3: seeded local scan; y = (C.h + u*D)*sz, written bf16.
__global__ __launch_bounds__(256) void scan3_kernel(
    const u16* __restrict__ szb, const u16* __restrict__ ub,
    const float* xdbl, const u16* __restrict__ dtb,
    const float* __restrict__ A_log, const float* __restrict__ Dp,
    const u16* __restrict__ hstart, u16* __restrict__ yb)
{
    __shared__ float Bs[CLEN][16];
    __shared__ float Cs[CLEN][16];
    const int blk  = blockIdx.x;
    const int dblk = blk & 3;
    const int c    = (blk >> 2) & (CHUNKS - 1);
    const int b    = blk >> 7;
    const int d    = dblk * 256 + threadIdx.x;
    const int mbase = b * L_ + c * CLEN;

#pragma unroll
    for (int q = 0; q < 2; ++q) {
        int idx = q * 256 + threadIdx.x;
        int tt = idx >> 4, ss = idx & 15;
        Bs[tt][ss] = xdbl[(size_t)(mbase + tt) * 64 + 32 + ss];
        Cs[tt][ss] = xdbl[(size_t)(mbase + tt) * 64 + 48 + ss];
    }
    float A[16];
    {
        float4 a4[4];
#pragma unroll
        for (int q = 0; q < 4; ++q) a4[q] = *(const float4*)&A_log[d * 16 + q * 4];
        const float* af = (const float*)a4;
#pragma unroll
        for (int s = 0; s < 16; ++s) A[s] = -__expf(af[s]);
    }
    const float Dval = Dp[d];

    float h[16];
    {
        size_t base = ((size_t)(b * CHUNKS + c) * DINNER + d) * 16;
        s16x8 p0 = *(const s16x8*)&hstart[base];
        s16x8 p1 = *(const s16x8*)&hstart[base + 8];
#pragma unroll
        for (int s = 0; s < 8; ++s) { h[s] = bf2f((u16)p0[s]); h[s+8] = bf2f((u16)p1[s]); }
    }
    __syncthreads();

    for (int t0 = 0; t0 < CLEN; t0 += 8) {
        float dt8[8], u8[8], sz8[8];
#pragma unroll
        for (int j = 0; j < 8; ++j) {
            int m = mbase + t0 + j;
            dt8[j] = bf2f(dtb[(size_t)m * DINNER + d]);
            u8[j]  = bf2f(ub [(size_t)m * DINNER + d]);
            sz8[j] = bf2f(szb[(size_t)m * DINNER + d]);
        }
#pragma unroll
        for (int j = 0; j < 8; ++j) {
            float dtv = dt8[j], dtu = dtv * u8[j];
            float Bt[16], Ct[16];
#pragma unroll
            for (int q = 0; q < 4; ++q) {
                *(float4*)&Bt[q*4] = *(const float4*)&Bs[t0 + j][q*4];
                *(float4*)&Ct[q*4] = *(const float4*)&Cs[t0 + j][q*4];
            }
            float yv = 0.f;
#pragma unroll
            for (int s = 0; s < 16; ++s) {
                float dA = __expf(dtv * A[s]);
                h[s] = dA * h[s] + dtu * Bt[s];
                yv += h[s] * Ct[s];
            }
            int m = mbase + t0 + j;
            yb[(size_t)m * DINNER + d] = f2bf((yv + u8[j] * Dval) * sz8[j]);
        }
    }
}

// ---------------------------------------------------------------------------
// Final LayerNorm over DMODEL=512, reading bf16 h.
__global__ __launch_bounds__(256) void ln_kernel(
    const u16* __restrict__ hb, const float* __restrict__ g,
    const float* __restrict__ bta, float* __restrict__ out)
{
    int m = blockIdx.x;
    size_t base = (size_t)m * DMODEL;
    int t = threadIdx.x;
    float v0 = bf2f(hb[base + t]);
    float v1 = bf2f(hb[base + t + 256]);
    float sum = v0 + v1, sq = v0*v0 + v1*v1;
#pragma unroll
    for (int off = 32; off; off >>= 1) {
        sum += __shfl_down(sum, off);
        sq  += __shfl_down(sq,  off);
    }
    __shared__ float ls[4], lq[4];
    int w = t >> 6;
    if ((t & 63) == 0) { ls[w] = sum; lq[w] = sq; }
    __syncthreads();
    sum = ls[0] + ls[1] + ls[2] + ls[3];
    sq  = lq[0] + lq[1] + lq[2] + lq[3];
    float mu  = sum * (1.f / DMODEL);
    float var = sq * (1.f / DMODEL) - mu * mu;
    float rs  = rsqrtf(var + 1e-5f);
    out[base + t]       = (v0 - mu) * rs * g[t]       + bta[t];
    out[base + t + 256] = (v1 - mu) * rs * g[t + 256] + bta[t + 256];
}

// ---------------------------------------------------------------------------
extern "C" void kernel_launch(void* const* d_in, const int* in_sizes, int n_in,
                              void* d_out, int out_size, void* d_ws, size_t ws_size,
                              hipStream_t stream)
{
    const float* x      = (const float*)d_in[0];
    const float* in_w   = (const float*)d_in[1];
    const float* in_b   = (const float*)d_in[2];
    const float* W_xz   = (const float*)d_in[3];
    const float* conv_w = (const float*)d_in[4];
    const float* conv_b = (const float*)d_in[5];
    const float* W_xp   = (const float*)d_in[6];
    const float* W_dt   = (const float*)d_in[7];
    const float* b_dt   = (const float*)d_in[8];
    const float* A_log  = (const float*)d_in[9];
    const float* D_par  = (const float*)d_in[10];
    const float* W_out  = (const float*)d_in[11];
    const float* ln_g   = (const float*)d_in[12];
    const float* ln_b   = (const float*)d_in[13];
    float* out = (float*)d_out;

    // Workspace layout (floats), total 15.25 M floats = 61 MB.
    float* ws      = (float*)d_ws;
    float* hbF     = ws;                    // 1 M  : hb bf16 (2M u16)
    float* hfinF   = hbF    + 1048576;      // 1 M  : hfinal/hstart bf16 (2M u16)
    float* xcbF    = hfinF  + 1048576;      // 2 M  : xc bf16
    float* szbF    = xcbF   + 2097152;      // 2 M  : silu(z) bf16
    float* ubF     = szbF   + 2097152;      // 2 M  : u bf16
    float* xdbl    = ubF    + 2097152;      // 256 K: fp32 (B/C cols + dtsum in cols 0..31)
    float* dtbF    = xdbl   + 262144;       // 2 M  : dt bf16
    float* ybF     = dtbF   + 2097152;      // 2 M  : y bf16
    float* wxzF    = ybF    + 2097152;      // 2 M  : Wxz bf16, all layers
    float* woutF   = wxzF   + 2097152;      // 1 M  : Wout bf16, all layers

    u16* hb     = (u16*)hbF;
    u16* hfinal = (u16*)hfinF;
    u16* xcb  = (u16*)xcbF;
    u16* szb  = (u16*)szbF;
    u16* ub   = (u16*)ubF;
    u16* dtb  = (u16*)dtbF;
    u16* yb   = (u16*)ybF;
    u16* wxzb  = (u16*)wxzF;
    u16* woutb = (u16*)woutF;

    // Convert all layers' GEMM weights to bf16 once.
    wconv_kernel<<<(DEPTH_*2048*DMODEL/8)/256, 256, 0, stream>>>(W_xz, wxzb);
    wconv_kernel<<<(DEPTH_*DMODEL*DINNER/8)/256, 256, 0, stream>>>(W_out, woutb);

    in_proj_kernel<<<MTOT*DMODEL/256, 256, 0, stream>>>(x, in_w, in_b, hb);

    for (int layer = 0; layer < DEPTH_; ++layer) {
        const float* cw   = conv_w + (size_t)layer * DINNER * DCONV;
        const float* cb   = conv_b + (size_t)layer * DINNER;
        const float* Wxp  = W_xp   + (size_t)layer * 64 * DINNER;
        const float* Wdt  = W_dt   + (size_t)layer * DINNER * DTRANK;
        const float* bdt  = b_dt   + (size_t)layer * DINNER;
        const float* Alog = A_log  + (size_t)layer * DINNER * DSTATE;
        const float* Dp   = D_par  + (size_t)layer * DINNER;
        const u16* wxzL   = wxzb  + (size_t)layer * 2048 * DMODEL;
        const u16* woutL  = woutb + (size_t)layer * DMODEL * DINNER;

        // xz GEMM (K=512), fused epilogue: bf16 xc + bf16 silu(z)
        gemm_bf16<128,128,1><<<dim3(2048/128, MTOT/128), 256, 0, stream>>>(
            hb, DMODEL, wxzL, DMODEL, xcb, szb, 0, DMODEL);
        // fused conv+silu -> u, x-proj -> B/C, dt GEMM + softplus -> dtb
        mid_kernel<<<MTOT/MROWS, 256, 0, stream>>>(
            xcb, cw, cb, Wxp, Wdt, bdt, ub, xdbl, dtb);
        // chunked selective scan
        scan1_kernel<<<B_*CHUNKS*(DINNER/256), 256, 0, stream>>>(ub, xdbl, dtb, Alog, hfinal, xdbl);
        scan2_kernel<<<(B_*DINNER*DSTATE)/256, 256, 0, stream>>>(hfinal, xdbl, Alog);
        scan3_kernel<<<B_*CHUNKS*(DINNER/256), 256, 0, stream>>>(szb, ub, xdbl, dtb, Alog, Dp, hfinal, yb);
        // h = y @ Wout^T (K=1024), 64x64 tile, direct bf16 epilogue
        gemm_bf16<64,64,2><<<dim3(DMODEL/64, MTOT/64), 256, 0, stream>>>(
            yb, DINNER, woutL, DINNER, hb, nullptr, DMODEL, DINNER);
    }

    ln_kernel<<<MTOT, 256, 0, stream>>>(hb, ln_g, ln_b, out);
}

// Round 10
// 700.375 us; speedup vs baseline: 1.0863x; 1.0863x over previous
//
#include <hip/hip_runtime.h>
#include <math.h>

// Problem constants (match reference)
#define B_      4
#define L_      1024
#define D_INNC  8      // D_IN
#define DMODEL  512
#define DEPTH_  4
#define DINNER  1024
#define DSTATE  16
#define DCONV   4
#define DTRANK  32
#define MTOT    (B_*L_)   // 4096
#define CHUNKS  32
#define CLEN    32        // L_/CHUNKS

typedef float f32x4 __attribute__((ext_vector_type(4)));
typedef short s16x8 __attribute__((ext_vector_type(8)));
typedef unsigned short u16;
typedef unsigned short u16x4v __attribute__((ext_vector_type(4)));

// fp32 -> bf16 round-to-nearest-even
__device__ __forceinline__ u16 f2bf(float v) {
    unsigned b = __float_as_uint(v);
    return (u16)((b + 0x7FFF + ((b >> 16) & 1)) >> 16);
}
__device__ __forceinline__ float bf2f(u16 h) {
    return __uint_as_float((unsigned)h << 16);
}

// ---------------------------------------------------------------------------
// h = x @ in_w^T + in_b  -> bf16 (4096 x 512, K=8)
__global__ __launch_bounds__(256) void in_proj_kernel(
    const float* __restrict__ x, const float* __restrict__ w,
    const float* __restrict__ bias, u16* __restrict__ hb)
{
    int idx = blockIdx.x * 256 + threadIdx.x;
    int m = idx / DMODEL, d = idx % DMODEL;
    const float* xr = x + m * D_INNC;
    const float* wr = w + d * D_INNC;
    float acc = bias[d];
#pragma unroll
    for (int k = 0; k < D_INNC; ++k) acc += xr[k] * wr[k];
    hb[idx] = f2bf(acc);
}

// ---------------------------------------------------------------------------
// fp32 -> bf16 array convert, 8 elems/thread.
__global__ __launch_bounds__(256) void wconv_kernel(
    const float* __restrict__ W, u16* __restrict__ Wb)
{
    int i = blockIdx.x * 256 + threadIdx.x;
    const float* src = W + (size_t)i * 8;
    float4 f0 = *(const float4*)src;
    float4 f1 = *(const float4*)(src + 4);
    float f[8] = {f0.x,f0.y,f0.z,f0.w,f1.x,f1.y,f1.z,f1.w};
    s16x8 hv;
#pragma unroll
    for (int e = 0; e < 8; ++e) hv[e] = (short)f2bf(f[e]);
    *(s16x8*)(Wb + (size_t)i * 8) = hv;
}

// ---------------------------------------------------------------------------
// bf16 MFMA NT GEMM: C[m,n] = sum_k A[m,k]*B[n,k].
// 256 thr = 4 waves (2x2); wave tile (BM/2)x(BN/2).
// MODE 1: xz epilogue — col<1024: bf16 xcb; col>=1024: silu -> bf16 szb.
// MODE 2: bf16 direct out to C0 (ldc).
template<int BM, int BN, int MODE>
__global__ __launch_bounds__(256, 2) void gemm_bf16(
    const u16* __restrict__ A, int lda,
    const u16* __restrict__ B, int ldb,
    void* __restrict__ C0, void* __restrict__ C1,
    int ldc, int K)
{
    constexpr int FM  = BM / 32;            // m-fragments per wave
    constexpr int FN  = BN / 32;            // n-fragments per wave
    constexpr int ACH = BM / 64;            // A 8-elem chunks per thread
    constexpr int BCH = BN / 64;            // B chunks per thread
    __shared__ __align__(16) u16 As[4*(BM+1)*8];
    __shared__ __align__(16) u16 Bs[4*(BN+1)*8];

    const int t    = threadIdx.x;
    const int lane = t & 63;
    const int w    = t >> 6;
    const int wm   = (w >> 1) * (BM / 2);
    const int wn   = (w & 1) * (BN / 2);
    const int quad = lane >> 4;
    const int l16  = lane & 15;
    const int m0   = blockIdx.y * BM;
    const int n0   = blockIdx.x * BN;

    f32x4 acc[FM][FN];
#pragma unroll
    for (int i = 0; i < FM; ++i)
#pragma unroll
        for (int j = 0; j < FN; ++j) acc[i][j] = (f32x4){0.f,0.f,0.f,0.f};

    s16x8 ra[ACH], rb[BCH];
#pragma unroll
    for (int c = 0; c < ACH; ++c) {
        int id = c*256 + t, row = id >> 2, kb = id & 3;
        ra[c] = *(const s16x8*)(A + (size_t)(m0 + row) * lda + kb*8);
    }
#pragma unroll
    for (int c = 0; c < BCH; ++c) {
        int id = c*256 + t, row = id >> 2, kb = id & 3;
        rb[c] = *(const s16x8*)(B + (size_t)(n0 + row) * ldb + kb*8);
    }

    for (int kk = 0; kk < K; kk += 32) {
        __syncthreads();
#pragma unroll
        for (int c = 0; c < ACH; ++c) {
            int id = c*256 + t, row = id >> 2, kb = id & 3;
            *(s16x8*)&As[(kb*(BM+1) + row) * 8] = ra[c];
        }
#pragma unroll
        for (int c = 0; c < BCH; ++c) {
            int id = c*256 + t, row = id >> 2, kb = id & 3;
            *(s16x8*)&Bs[(kb*(BN+1) + row) * 8] = rb[c];
        }
        __syncthreads();
        int kn = kk + 32;
        if (kn < K) {   // prefetch next K-slice, overlaps MFMA below
#pragma unroll
            for (int c = 0; c < ACH; ++c) {
                int id = c*256 + t, row = id >> 2, kb = id & 3;
                ra[c] = *(const s16x8*)(A + (size_t)(m0 + row) * lda + kn + kb*8);
            }
#pragma unroll
            for (int c = 0; c < BCH; ++c) {
                int id = c*256 + t, row = id >> 2, kb = id & 3;
                rb[c] = *(const s16x8*)(B + (size_t)(n0 + row) * ldb + kn + kb*8);
            }
        }
        s16x8 afr[FM], bfr[FN];
#pragma unroll
        for (int i = 0; i < FM; ++i)
            afr[i] = *(const s16x8*)&As[(quad*(BM+1) + wm + i*16 + l16) * 8];
#pragma unroll
        for (int j = 0; j < FN; ++j)
            bfr[j] = *(const s16x8*)&Bs[(quad*(BN+1) + wn + j*16 + l16) * 8];
#pragma unroll
        for (int i = 0; i < FM; ++i)
#pragma unroll
            for (int j = 0; j < FN; ++j)
                acc[i][j] = __builtin_amdgcn_mfma_f32_16x16x32_bf16(afr[i], bfr[j], acc[i][j], 0, 0, 0);
    }

    // epilogue: C/D layout col=lane&15, row=quad*4+reg
    if (MODE == 2) {
        u16* C = (u16*)C0;
#pragma unroll
        for (int i = 0; i < FM; ++i)
#pragma unroll
            for (int j = 0; j < FN; ++j) {
                int col = n0 + wn + j*16 + l16;
#pragma unroll
                for (int r = 0; r < 4; ++r) {
                    int row = m0 + wm + i*16 + quad*4 + r;
                    C[(size_t)row * ldc + col] = f2bf(acc[i][j][r]);
                }
            }
    } else {
        u16* xcb = (u16*)C0;
        u16* szb = (u16*)C1;
#pragma unroll
        for (int i = 0; i < FM; ++i)
#pragma unroll
            for (int j = 0; j < FN; ++j) {
                int col = n0 + wn + j*16 + l16;
                bool isz = col >= DINNER;
                int cc = col & (DINNER - 1);
                u16* dst = isz ? szb : xcb;
#pragma unroll
                for (int r = 0; r < 4; ++r) {
                    int row = m0 + wm + i*16 + quad*4 + r;
                    float v = acc[i][j][r];
                    if (isz) v = v / (1.f + __expf(-v));   // silu(z)
                    dst[(size_t)row * DINNER + cc] = f2bf(v);
                }
            }
    }
}

// ---------------------------------------------------------------------------
// Depthwise causal conv (k=4) + bias + SiLU; bf16 in/out. 2 d-channels/thread.
__global__ __launch_bounds__(256) void conv_silu_kernel(
    const u16* __restrict__ xcb, const float* __restrict__ cw,
    const float* __restrict__ cb, u16* __restrict__ ub)
{
    int idx = (blockIdx.x * 256 + threadIdx.x) * 2;   // MTOT*DINNER, even
    int m = idx >> 10;
    int d = idx & (DINNER - 1);
    int l = m & (L_ - 1);

    const float4 w0 = *(const float4*)&cw[d * 4];
    const float4 w1 = *(const float4*)&cw[(d + 1) * 4];
    float a0 = cb[d], a1 = cb[d + 1];
#pragma unroll
    for (int k = 0; k < 4; ++k) {
        int lag = 3 - k;
        if (l >= lag) {
            unsigned v = *(const unsigned*)&xcb[(size_t)(m - lag) * DINNER + d];
            float x0 = bf2f((u16)(v & 0xffff));
            float x1 = bf2f((u16)(v >> 16));
            float wk0 = (&w0.x)[k], wk1 = (&w1.x)[k];
            a0 += x0 * wk0; a1 += x1 * wk1;
        }
    }
    a0 = a0 / (1.f + __expf(-a0));
    a1 = a1 / (1.f + __expf(-a1));
    unsigned pack = (unsigned)f2bf(a0) | ((unsigned)f2bf(a1) << 16);
    *(unsigned*)&ub[idx] = pack;
}

// ---------------------------------------------------------------------------
// x-proj partial GEMM: part[p][m][n] = sum_{k in split p} u[m,k]*W[n,k]
// u is bf16 (converted to fp32 during LDS staging). BM=16, N=64, K-split 4x256.
__global__ __launch_bounds__(256) void xp_kernel(
    const u16* __restrict__ ub, const float* __restrict__ W,
    float* __restrict__ part)
{
    __shared__ float As[16][68];
    __shared__ float Ws[64][65];
    const int p  = blockIdx.x;
    const int m0 = blockIdx.y * 16;
    const int t  = threadIdx.x;
    const int kb = p * 256;
    const int n  = t & 63;
    const int mi = t >> 6;
    float acc[4] = {0.f, 0.f, 0.f, 0.f};

    for (int kt = 0; kt < 256; kt += 64) {
        const int k0 = kb + kt;
        __syncthreads();
        {   // stage A tile 16x64 (bf16 -> fp32)
            int r = t >> 4, cc = t & 15;
            u16x4v v = *(const u16x4v*)&ub[(size_t)(m0 + r) * DINNER + k0 + cc*4];
#pragma unroll
            for (int e = 0; e < 4; ++e) As[r][cc*4+e] = bf2f(v[e]);
        }
        {   // stage W tile 64x64
            int r = t >> 2, f = t & 3;
#pragma unroll
            for (int q = 0; q < 4; ++q) {
                float4 v = *(const float4*)&W[(size_t)r * DINNER + k0 + f*16 + q*4];
                Ws[r][f*16+q*4+0] = v.x; Ws[r][f*16+q*4+1] = v.y;
                Ws[r][f*16+q*4+2] = v.z; Ws[r][f*16+q*4+3] = v.w;
            }
        }
        __syncthreads();
#pragma unroll 8
        for (int kk = 0; kk < 64; ++kk) {
            float w = Ws[n][kk];
#pragma unroll
            for (int j = 0; j < 4; ++j) acc[j] += As[mi*4+j][kk] * w;
        }
    }
#pragma unroll
    for (int j = 0; j < 4; ++j)
        part[((size_t)p * MTOT + m0 + mi*4 + j) * 64 + n] = acc[j];
}

// ---------------------------------------------------------------------------
// Fused: sum 4 K-split partials (-> B/C cols of xdbl) + dt GEMM + softplus.
// 8 m-rows per block.
__global__ __launch_bounds__(256) void dtsum_kernel(
    const float* __restrict__ part, const float* __restrict__ Wdt,
    const float* __restrict__ bdt, float* __restrict__ xdbl,
    u16* __restrict__ dtb)
{
    __shared__ float a[8][64];
    const int m0 = blockIdx.x * 8;
    const int t = threadIdx.x;
#pragma unroll
    for (int e = 0; e < 2; ++e) {
        int id = e * 256 + t;
        int r = id >> 6, c = id & 63;
        float s = 0.f;
#pragma unroll
        for (int p = 0; p < 4; ++p)
            s += part[((size_t)p * MTOT + m0 + r) * 64 + c];
        a[r][c] = s;
        if (c >= 32) xdbl[(size_t)(m0 + r) * 64 + c] = s;   // B,C for scans
    }
    __syncthreads();
    for (int n = t; n < DINNER; n += 256) {
        const float* w = Wdt + (size_t)n * DTRANK;
        float bb = bdt[n];
        float acc[8];
#pragma unroll
        for (int r = 0; r < 8; ++r) acc[r] = bb;
#pragma unroll
        for (int k = 0; k < DTRANK; ++k) {
            float wk = w[k];
#pragma unroll
            for (int r = 0; r < 8; ++r) acc[r] += a[r][k] * wk;
        }
#pragma unroll
        for (int r = 0; r < 8; ++r) {
            float v = acc[r];
            float sp = (v > 20.f) ? v : log1pf(expf(v));
            dtb[(size_t)(m0 + r) * DINNER + n] = f2bf(sp);
        }
    }
}

// ---------------------------------------------------------------------------
// Chunked scan pass 1 — one lane per (b,c,d), 16 states in VGPRs.
// hfinal stored bf16; dt-sums stored into dead cols 0..31 of xdbl.
__global__ __launch_bounds__(256) void scan1_kernel(
    const u16* __restrict__ ub, const float* xdbl,
    const u16* __restrict__ dtb, const float* __restrict__ A_log,
    u16* __restrict__ hfinal, float* dtsum_out)
{
    __shared__ float Bs[CLEN][16];
    const int blk  = blockIdx.x;              // b*128 + c*4 + dblk
    const int dblk = blk & 3;
    const int c    = (blk >> 2) & (CHUNKS - 1);
    const int b    = blk >> 7;
    const int d    = dblk * 256 + threadIdx.x;
    const int mbase = b * L_ + c * CLEN;

#pragma unroll
    for (int q = 0; q < 2; ++q) {
        int idx = q * 256 + threadIdx.x;
        int tt = idx >> 4, ss = idx & 15;
        Bs[tt][ss] = xdbl[(size_t)(mbase + tt) * 64 + 32 + ss];
    }
    float A[16];
    {
        float4 a4[4];
#pragma unroll
        for (int q = 0; q < 4; ++q) a4[q] = *(const float4*)&A_log[d * 16 + q * 4];
        const float* af = (const float*)a4;
#pragma unroll
        for (int s = 0; s < 16; ++s) A[s] = -__expf(af[s]);
    }
    __syncthreads();

    float h[16];
#pragma unroll
    for (int s = 0; s < 16; ++s) h[s] = 0.f;
    float dts = 0.f;

    for (int t0 = 0; t0 < CLEN; t0 += 8) {
        float dt8[8], u8[8];
#pragma unroll
        for (int j = 0; j < 8; ++j) {
            int m = mbase + t0 + j;
            dt8[j] = bf2f(dtb[(size_t)m * DINNER + d]);
            u8[j]  = bf2f(ub [(size_t)m * DINNER + d]);
        }
#pragma unroll
        for (int j = 0; j < 8; ++j) {
            float dtv = dt8[j], dtu = dtv * u8[j];
            dts += dtv;
            float Bt[16];
#pragma unroll
            for (int q = 0; q < 4; ++q)
                *(float4*)&Bt[q*4] = *(const float4*)&Bs[t0 + j][q*4];
#pragma unroll
            for (int s = 0; s < 16; ++s) {
                float dA = __expf(dtv * A[s]);
                h[s] = dA * h[s] + dtu * Bt[s];
            }
        }
    }
    size_t base = ((size_t)(b * CHUNKS + c) * DINNER + d) * 16;
    s16x8 p0, p1;
#pragma unroll
    for (int s = 0; s < 8; ++s) { p0[s] = (short)f2bf(h[s]); p1[s] = (short)f2bf(h[s+8]); }
    *(s16x8*)&hfinal[base]     = p0;
    *(s16x8*)&hfinal[base + 8] = p1;
    int i = (b * CHUNKS + c) * DINNER + d;
    dtsum_out[(i >> 5) * 64 + (i & 31)] = dts;
}

// Pass 2: sequential chunk fix-up (bf16 states, fp32 math).
__global__ __launch_bounds__(256) void scan2_kernel(
    u16* __restrict__ hfinal, const float* __restrict__ dtsum,
    const float* __restrict__ A_log)
{
    int t = blockIdx.x * 256 + threadIdx.x;   // 65536 = B_*DINNER*DSTATE
    int s = t & 15, d = (t >> 4) & (DINNER - 1), b = t >> 14;
    float As = -__expf(A_log[d * DSTATE + s]);
    float h = 0.f;
    for (int c0 = 0; c0 < CHUNKS; c0 += 8) {
        float hf8[8], dts8[8];
#pragma unroll
        for (int j = 0; j < 8; ++j) {
            int c = c0 + j;
            int i = (b * CHUNKS + c) * DINNER + d;
            dts8[j] = dtsum[(i >> 5) * 64 + (i & 31)];
            hf8[j]  = bf2f(hfinal[((size_t)i) * 16 + s]);
        }
#pragma unroll
        for (int j = 0; j < 8; ++j) {
            int c = c0 + j;
            size_t idx = ((size_t)((b * CHUNKS + c) * DINNER + d)) * 16 + s;
            hfinal[idx] = f2bf(h);
            h = __expf(As * dts8[j]) * h + hf8[j];
        }
    }
}

// Pass 3: seeded local scan; y = (C.h + u*D)*sz, written bf16.
__global__ __launch_bounds__(256) void scan3_kernel(
    const u16* __restrict__ szb, const u16* __restrict__ ub,
    const float* xdbl, const u16* __restrict__ dtb,
    const float* __restrict__ A_log, const float* __restrict__ Dp,
    const u16* __restrict__ hstart, u16* __restrict__ yb)
{
    __shared__ float Bs[CLEN][16];
    __shared__ float Cs[CLEN][16];
    const int blk  = blockIdx.x;
    const int dblk = blk & 3;
    const int c    = (blk >> 2) & (CHUNKS - 1);
    const int b    = blk >> 7;
    const int d    = dblk * 256 + threadIdx.x;
    const int mbase = b * L_ + c * CLEN;

#pragma unroll
    for (int q = 0; q < 2; ++q) {
        int idx = q * 256 + threadIdx.x;
        int tt = idx >> 4, ss = idx & 15;
        Bs[tt][ss] = xdbl[(size_t)(mbase + tt) * 64 + 32 + ss];
        Cs[tt][ss] = xdbl[(size_t)(mbase + tt) * 64 + 48 + ss];
    }
    float A[16];
    {
        float4 a4[4];
#pragma unroll
        for (int q = 0; q < 4; ++q) a4[q] = *(const float4*)&A_log[d * 16 + q * 4];
        const float* af = (const float*)a4;
#pragma unroll
        for (int s = 0; s < 16; ++s) A[s] = -__expf(af[s]);
    }
    const float Dval = Dp[d];

    float h[16];
    {
        size_t base = ((size_t)(b * CHUNKS + c) * DINNER + d) * 16;
        s16x8 p0 = *(const s16x8*)&hstart[base];
        s16x8 p1 = *(const s16x8*)&hstart[base + 8];
#pragma unroll
        for (int s = 0; s < 8; ++s) { h[s] = bf2f((u16)p0[s]); h[s+8] = bf2f((u16)p1[s]); }
    }
    __syncthreads();

    for (int t0 = 0; t0 < CLEN; t0 += 8) {
        float dt8[8], u8[8], sz8[8];
#pragma unroll
        for (int j = 0; j < 8; ++j) {
            int m = mbase + t0 + j;
            dt8[j] = bf2f(dtb[(size_t)m * DINNER + d]);
            u8[j]  = bf2f(ub [(size_t)m * DINNER + d]);
            sz8[j] = bf2f(szb[(size_t)m * DINNER + d]);
        }
#pragma unroll
        for (int j = 0; j < 8; ++j) {
            float dtv = dt8[j], dtu = dtv * u8[j];
            float Bt[16], Ct[16];
#pragma unroll
            for (int q = 0; q < 4; ++q) {
                *(float4*)&Bt[q*4] = *(const float4*)&Bs[t0 + j][q*4];
                *(float4*)&Ct[q*4] = *(const float4*)&Cs[t0 + j][q*4];
            }
            float yv = 0.f;
#pragma unroll
            for (int s = 0; s < 16; ++s) {
                float dA = __expf(dtv * A[s]);
                h[s] = dA * h[s] + dtu * Bt[s];
                yv += h[s] * Ct[s];
            }
            int m = mbase + t0 + j;
            yb[(size_t)m * DINNER + d] = f2bf((yv + u8[j] * Dval) * sz8[j]);
        }
    }
}

// ---------------------------------------------------------------------------
// Final LayerNorm over DMODEL=512, reading bf16 h.
__global__ __launch_bounds__(256) void ln_kernel(
    const u16* __restrict__ hb, const float* __restrict__ g,
    const float* __restrict__ bta, float* __restrict__ out)
{
    int m = blockIdx.x;
    size_t base = (size_t)m * DMODEL;
    int t = threadIdx.x;
    float v0 = bf2f(hb[base + t]);
    float v1 = bf2f(hb[base + t + 256]);
    float sum = v0 + v1, sq = v0*v0 + v1*v1;
#pragma unroll
    for (int off = 32; off; off >>= 1) {
        sum += __shfl_down(sum, off);
        sq  += __shfl_down(sq,  off);
    }
    __shared__ float ls[4], lq[4];
    int w = t >> 6;
    if ((t & 63) == 0) { ls[w] = sum; lq[w] = sq; }
    __syncthreads();
    sum = ls[0] + ls[1] + ls[2] + ls[3];
    sq  = lq[0] + lq[1] + lq[2] + lq[3];
    float mu  = sum * (1.f / DMODEL);
    float var = sq * (1.f / DMODEL) - mu * mu;
    float rs  = rsqrtf(var + 1e-5f);
    out[base + t]       = (v0 - mu) * rs * g[t]       + bta[t];
    out[base + t + 256] = (v1 - mu) * rs * g[t + 256] + bta[t + 256];
}

// ---------------------------------------------------------------------------
extern "C" void kernel_launch(void* const* d_in, const int* in_sizes, int n_in,
                              void* d_out, int out_size, void* d_ws, size_t ws_size,
                              hipStream_t stream)
{
    const float* x      = (const float*)d_in[0];
    const float* in_w   = (const float*)d_in[1];
    const float* in_b   = (const float*)d_in[2];
    const float* W_xz   = (const float*)d_in[3];
    const float* conv_w = (const float*)d_in[4];
    const float* conv_b = (const float*)d_in[5];
    const float* W_xp   = (const float*)d_in[6];
    const float* W_dt   = (const float*)d_in[7];
    const float* b_dt   = (const float*)d_in[8];
    const float* A_log  = (const float*)d_in[9];
    const float* D_par  = (const float*)d_in[10];
    const float* W_out  = (const float*)d_in[11];
    const float* ln_g   = (const float*)d_in[12];
    const float* ln_b   = (const float*)d_in[13];
    float* out = (float*)d_out;

    // Workspace layout (floats), total 16.25 M floats = 65 MB.
    float* ws      = (float*)d_ws;
    float* hbF     = ws;                    // 1 M  : hb bf16 (2M u16)
    float* hfinF   = hbF    + 1048576;      // 1 M  : hfinal/hstart bf16 (2M u16)
    float* xcbF    = hfinF  + 1048576;      // 2 M  : xc bf16
    float* szbF    = xcbF   + 2097152;      // 2 M  : silu(z) bf16
    float* ubF     = szbF   + 2097152;      // 2 M  : u bf16
    float* xdbl    = ubF    + 2097152;      // 256 K: fp32 (B/C cols + dtsum in cols 0..31)
    float* dtbF    = xdbl   + 262144;       // 2 M  : dt bf16
    float* ybF     = dtbF   + 2097152;      // 2 M  : y bf16
    float* xpart   = ybF    + 2097152;      // 1 M  : x-proj K-split partials (4 x 256K)
    float* wxzF    = xpart  + 1048576;      // 2 M  : Wxz bf16, all layers
    float* woutF   = wxzF   + 2097152;      // 1 M  : Wout bf16, all layers

    u16* hb     = (u16*)hbF;
    u16* hfinal = (u16*)hfinF;
    u16* xcb  = (u16*)xcbF;
    u16* szb  = (u16*)szbF;
    u16* ub   = (u16*)ubF;
    u16* dtb  = (u16*)dtbF;
    u16* yb   = (u16*)ybF;
    u16* wxzb  = (u16*)wxzF;
    u16* woutb = (u16*)woutF;

    // Convert all layers' GEMM weights to bf16 once.
    wconv_kernel<<<(DEPTH_*2048*DMODEL/8)/256, 256, 0, stream>>>(W_xz, wxzb);
    wconv_kernel<<<(DEPTH_*DMODEL*DINNER/8)/256, 256, 0, stream>>>(W_out, woutb);

    in_proj_kernel<<<MTOT*DMODEL/256, 256, 0, stream>>>(x, in_w, in_b, hb);

    for (int layer = 0; layer < DEPTH_; ++layer) {
        const float* cw   = conv_w + (size_t)layer * DINNER * DCONV;
        const float* cb   = conv_b + (size_t)layer * DINNER;
        const float* Wxp  = W_xp   + (size_t)layer * 64 * DINNER;
        const float* Wdt  = W_dt   + (size_t)layer * DINNER * DTRANK;
        const float* bdt  = b_dt   + (size_t)layer * DINNER;
        const float* Alog = A_log  + (size_t)layer * DINNER * DSTATE;
        const float* Dp   = D_par  + (size_t)layer * DINNER;
        const u16* wxzL   = wxzb  + (size_t)layer * 2048 * DMODEL;
        const u16* woutL  = woutb + (size_t)layer * DMODEL * DINNER;

        // xz GEMM (K=512), fused epilogue: bf16 xc + bf16 silu(z)
        gemm_bf16<128,128,1><<<dim3(2048/128, MTOT/128), 256, 0, stream>>>(
            hb, DMODEL, wxzL, DMODEL, xcb, szb, 0, DMODEL);
        // u = silu(conv(xc) + cb)
        conv_silu_kernel<<<MTOT*DINNER/2/256, 256, 0, stream>>>(xcb, cw, cb, ub);
        // x-proj K-split x4 partials
        xp_kernel<<<dim3(4, MTOT/16), 256, 0, stream>>>(ub, Wxp, xpart);
        // fused partial-sum + dt GEMM + softplus
        dtsum_kernel<<<MTOT/8, 256, 0, stream>>>(xpart, Wdt, bdt, xdbl, dtb);
        // chunked selective scan (bf16 chunk states)
        scan1_kernel<<<B_*CHUNKS*(DINNER/256), 256, 0, stream>>>(ub, xdbl, dtb, Alog, hfinal, xdbl);
        scan2_kernel<<<(B_*DINNER*DSTATE)/256, 256, 0, stream>>>(hfinal, xdbl, Alog);
        scan3_kernel<<<B_*CHUNKS*(DINNER/256), 256, 0, stream>>>(szb, ub, xdbl, dtb, Alog, Dp, hfinal, yb);
        // h = y @ Wout^T (K=1024), 64x64 tile, direct bf16 epilogue
        gemm_bf16<64,64,2><<<dim3(DMODEL/64, MTOT/64), 256, 0, stream>>>(
            yb, DINNER, woutL, DINNER, hb, nullptr, DMODEL, DINNER);
    }

    ln_kernel<<<MTOT, 256, 0, stream>>>(hb, ln_g, ln_b, out);
}

// Round 11
// 699.673 us; speedup vs baseline: 1.0873x; 1.0010x over previous
//
#include <hip/hip_runtime.h>
#include <math.h>

// Problem constants (match reference)
#define B_      4
#define L_      1024
#define D_INNC  8      // D_IN
#define DMODEL  512
#define DEPTH_  4
#define DINNER  1024
#define DSTATE  16
#define DCONV   4
#define DTRANK  32
#define MTOT    (B_*L_)   // 4096
#define CHUNKS  32
#define CLEN    32        // L_/CHUNKS

typedef float f32x4 __attribute__((ext_vector_type(4)));
typedef short s16x8 __attribute__((ext_vector_type(8)));
typedef unsigned short u16;
typedef unsigned short u16x4v __attribute__((ext_vector_type(4)));

// fp32 -> bf16 round-to-nearest-even
__device__ __forceinline__ u16 f2bf(float v) {
    unsigned b = __float_as_uint(v);
    return (u16)((b + 0x7FFF + ((b >> 16) & 1)) >> 16);
}
__device__ __forceinline__ float bf2f(u16 h) {
    return __uint_as_float((unsigned)h << 16);
}

// ---------------------------------------------------------------------------
// h = x @ in_w^T + in_b  -> bf16 (4096 x 512, K=8)
__global__ __launch_bounds__(256) void in_proj_kernel(
    const float* __restrict__ x, const float* __restrict__ w,
    const float* __restrict__ bias, u16* __restrict__ hb)
{
    int idx = blockIdx.x * 256 + threadIdx.x;
    int m = idx / DMODEL, d = idx % DMODEL;
    const float* xr = x + m * D_INNC;
    const float* wr = w + d * D_INNC;
    float acc = bias[d];
#pragma unroll
    for (int k = 0; k < D_INNC; ++k) acc += xr[k] * wr[k];
    hb[idx] = f2bf(acc);
}

// ---------------------------------------------------------------------------
// fp32 -> bf16 array convert, 8 elems/thread.
__global__ __launch_bounds__(256) void wconv_kernel(
    const float* __restrict__ W, u16* __restrict__ Wb)
{
    int i = blockIdx.x * 256 + threadIdx.x;
    const float* src = W + (size_t)i * 8;
    float4 f0 = *(const float4*)src;
    float4 f1 = *(const float4*)(src + 4);
    float f[8] = {f0.x,f0.y,f0.z,f0.w,f1.x,f1.y,f1.z,f1.w};
    s16x8 hv;
#pragma unroll
    for (int e = 0; e < 8; ++e) hv[e] = (short)f2bf(f[e]);
    *(s16x8*)(Wb + (size_t)i * 8) = hv;
}

// ---------------------------------------------------------------------------
// One-time transpose: WdtT[l][k][n] = Wdt[l][n][k]. (DEPTH x 1024 x 32)
__global__ __launch_bounds__(256) void wdtT_kernel(
    const float* __restrict__ Wdt, float* __restrict__ WdtT)
{
    int idx = blockIdx.x * 256 + threadIdx.x;   // DEPTH*DINNER*DTRANK
    int l = idx >> 15;
    int rem = idx & 32767;
    int n = rem >> 5, k = rem & 31;
    WdtT[(size_t)l * 32768 + k * DINNER + n] = Wdt[idx];
}

// ---------------------------------------------------------------------------
// bf16 MFMA NT GEMM: C[m,n] = sum_k A[m,k]*B[n,k].
// 256 thr = 4 waves (2x2); wave tile (BM/2)x(BN/2).
// MODE 1: xz epilogue — col<1024: bf16 xcb; col>=1024: silu -> bf16 szb.
// MODE 2: bf16 direct out to C0 (ldc).
template<int BM, int BN, int MODE>
__global__ __launch_bounds__(256, 2) void gemm_bf16(
    const u16* __restrict__ A, int lda,
    const u16* __restrict__ B, int ldb,
    void* __restrict__ C0, void* __restrict__ C1,
    int ldc, int K)
{
    constexpr int FM  = BM / 32;            // m-fragments per wave
    constexpr int FN  = BN / 32;            // n-fragments per wave
    constexpr int ACH = BM / 64;            // A 8-elem chunks per thread
    constexpr int BCH = BN / 64;            // B chunks per thread
    __shared__ __align__(16) u16 As[4*(BM+1)*8];
    __shared__ __align__(16) u16 Bs[4*(BN+1)*8];

    const int t    = threadIdx.x;
    const int lane = t & 63;
    const int w    = t >> 6;
    const int wm   = (w >> 1) * (BM / 2);
    const int wn   = (w & 1) * (BN / 2);
    const int quad = lane >> 4;
    const int l16  = lane & 15;
    const int m0   = blockIdx.y * BM;
    const int n0   = blockIdx.x * BN;

    f32x4 acc[FM][FN];
#pragma unroll
    for (int i = 0; i < FM; ++i)
#pragma unroll
        for (int j = 0; j < FN; ++j) acc[i][j] = (f32x4){0.f,0.f,0.f,0.f};

    s16x8 ra[ACH], rb[BCH];
#pragma unroll
    for (int c = 0; c < ACH; ++c) {
        int id = c*256 + t, row = id >> 2, kb = id & 3;
        ra[c] = *(const s16x8*)(A + (size_t)(m0 + row) * lda + kb*8);
    }
#pragma unroll
    for (int c = 0; c < BCH; ++c) {
        int id = c*256 + t, row = id >> 2, kb = id & 3;
        rb[c] = *(const s16x8*)(B + (size_t)(n0 + row) * ldb + kb*8);
    }

    for (int kk = 0; kk < K; kk += 32) {
        __syncthreads();
#pragma unroll
        for (int c = 0; c < ACH; ++c) {
            int id = c*256 + t, row = id >> 2, kb = id & 3;
            *(s16x8*)&As[(kb*(BM+1) + row) * 8] = ra[c];
        }
#pragma unroll
        for (int c = 0; c < BCH; ++c) {
            int id = c*256 + t, row = id >> 2, kb = id & 3;
            *(s16x8*)&Bs[(kb*(BN+1) + row) * 8] = rb[c];
        }
        __syncthreads();
        int kn = kk + 32;
        if (kn < K) {   // prefetch next K-slice, overlaps MFMA below
#pragma unroll
            for (int c = 0; c < ACH; ++c) {
                int id = c*256 + t, row = id >> 2, kb = id & 3;
                ra[c] = *(const s16x8*)(A + (size_t)(m0 + row) * lda + kn + kb*8);
            }
#pragma unroll
            for (int c = 0; c < BCH; ++c) {
                int id = c*256 + t, row = id >> 2, kb = id & 3;
                rb[c] = *(const s16x8*)(B + (size_t)(n0 + row) * ldb + kn + kb*8);
            }
        }
        s16x8 afr[FM], bfr[FN];
#pragma unroll
        for (int i = 0; i < FM; ++i)
            afr[i] = *(const s16x8*)&As[(quad*(BM+1) + wm + i*16 + l16) * 8];
#pragma unroll
        for (int j = 0; j < FN; ++j)
            bfr[j] = *(const s16x8*)&Bs[(quad*(BN+1) + wn + j*16 + l16) * 8];
#pragma unroll
        for (int i = 0; i < FM; ++i)
#pragma unroll
            for (int j = 0; j < FN; ++j)
                acc[i][j] = __builtin_amdgcn_mfma_f32_16x16x32_bf16(afr[i], bfr[j], acc[i][j], 0, 0, 0);
    }

    // epilogue: C/D layout col=lane&15, row=quad*4+reg
    if (MODE == 2) {
        u16* C = (u16*)C0;
#pragma unroll
        for (int i = 0; i < FM; ++i)
#pragma unroll
            for (int j = 0; j < FN; ++j) {
                int col = n0 + wn + j*16 + l16;
#pragma unroll
                for (int r = 0; r < 4; ++r) {
                    int row = m0 + wm + i*16 + quad*4 + r;
                    C[(size_t)row * ldc + col] = f2bf(acc[i][j][r]);
                }
            }
    } else {
        u16* xcb = (u16*)C0;
        u16* szb = (u16*)C1;
#pragma unroll
        for (int i = 0; i < FM; ++i)
#pragma unroll
            for (int j = 0; j < FN; ++j) {
                int col = n0 + wn + j*16 + l16;
                bool isz = col >= DINNER;
                int cc = col & (DINNER - 1);
                u16* dst = isz ? szb : xcb;
#pragma unroll
                for (int r = 0; r < 4; ++r) {
                    int row = m0 + wm + i*16 + quad*4 + r;
                    float v = acc[i][j][r];
                    if (isz) v = v / (1.f + __expf(-v));   // silu(z)
                    dst[(size_t)row * DINNER + cc] = f2bf(v);
                }
            }
    }
}

// ---------------------------------------------------------------------------
// Depthwise causal conv (k=4) + bias + SiLU; bf16 in/out. 2 d-channels/thread.
__global__ __launch_bounds__(256) void conv_silu_kernel(
    const u16* __restrict__ xcb, const float* __restrict__ cw,
    const float* __restrict__ cb, u16* __restrict__ ub)
{
    int idx = (blockIdx.x * 256 + threadIdx.x) * 2;   // MTOT*DINNER, even
    int m = idx >> 10;
    int d = idx & (DINNER - 1);
    int l = m & (L_ - 1);

    const float4 w0 = *(const float4*)&cw[d * 4];
    const float4 w1 = *(const float4*)&cw[(d + 1) * 4];
    float a0 = cb[d], a1 = cb[d + 1];
#pragma unroll
    for (int k = 0; k < 4; ++k) {
        int lag = 3 - k;
        if (l >= lag) {
            unsigned v = *(const unsigned*)&xcb[(size_t)(m - lag) * DINNER + d];
            float x0 = bf2f((u16)(v & 0xffff));
            float x1 = bf2f((u16)(v >> 16));
            float wk0 = (&w0.x)[k], wk1 = (&w1.x)[k];
            a0 += x0 * wk0; a1 += x1 * wk1;
        }
    }
    a0 = a0 / (1.f + __expf(-a0));
    a1 = a1 / (1.f + __expf(-a1));
    unsigned pack = (unsigned)f2bf(a0) | ((unsigned)f2bf(a1) << 16);
    *(unsigned*)&ub[idx] = pack;
}

// ---------------------------------------------------------------------------
// x-proj partial GEMM: part[p][m][n] = sum_{k in split p} u[m,k]*W[n,k]
// u is bf16 (converted to fp32 during LDS staging). BM=16, N=64, K-split 4x256.
__global__ __launch_bounds__(256) void xp_kernel(
    const u16* __restrict__ ub, const float* __restrict__ W,
    float* __restrict__ part)
{
    __shared__ float As[16][68];
    __shared__ float Ws[64][65];
    const int p  = blockIdx.x;
    const int m0 = blockIdx.y * 16;
    const int t  = threadIdx.x;
    const int kb = p * 256;
    const int n  = t & 63;
    const int mi = t >> 6;
    float acc[4] = {0.f, 0.f, 0.f, 0.f};

    for (int kt = 0; kt < 256; kt += 64) {
        const int k0 = kb + kt;
        __syncthreads();
        {   // stage A tile 16x64 (bf16 -> fp32)
            int r = t >> 4, cc = t & 15;
            u16x4v v = *(const u16x4v*)&ub[(size_t)(m0 + r) * DINNER + k0 + cc*4];
#pragma unroll
            for (int e = 0; e < 4; ++e) As[r][cc*4+e] = bf2f(v[e]);
        }
        {   // stage W tile 64x64
            int r = t >> 2, f = t & 3;
#pragma unroll
            for (int q = 0; q < 4; ++q) {
                float4 v = *(const float4*)&W[(size_t)r * DINNER + k0 + f*16 + q*4];
                Ws[r][f*16+q*4+0] = v.x; Ws[r][f*16+q*4+1] = v.y;
                Ws[r][f*16+q*4+2] = v.z; Ws[r][f*16+q*4+3] = v.w;
            }
        }
        __syncthreads();
#pragma unroll 8
        for (int kk = 0; kk < 64; ++kk) {
            float w = Ws[n][kk];
#pragma unroll
            for (int j = 0; j < 4; ++j) acc[j] += As[mi*4+j][kk] * w;
        }
    }
#pragma unroll
    for (int j = 0; j < 4; ++j)
        part[((size_t)p * MTOT + m0 + mi*4 + j) * 64 + n] = acc[j];
}

// ---------------------------------------------------------------------------
// Fused: sum 4 K-split partials (-> B/C cols of xdbl) + dt GEMM + softplus.
// 8 m-rows per block. Wdt is pre-transposed: WdtT[k][n] (k=0..31, n=0..1023)
// so the inner loads are coalesced across threads (n = nbase + t).
__global__ __launch_bounds__(256) void dtsum_kernel(
    const float* __restrict__ part, const float* __restrict__ WdtT,
    const float* __restrict__ bdt, float* __restrict__ xdbl,
    u16* __restrict__ dtb)
{
    __shared__ float a[8][64];
    const int m0 = blockIdx.x * 8;
    const int t = threadIdx.x;
#pragma unroll
    for (int e = 0; e < 2; ++e) {
        int id = e * 256 + t;
        int r = id >> 6, c = id & 63;
        float s = 0.f;
#pragma unroll
        for (int p = 0; p < 4; ++p)
            s += part[((size_t)p * MTOT + m0 + r) * 64 + c];
        a[r][c] = s;
        if (c >= 32) xdbl[(size_t)(m0 + r) * 64 + c] = s;   // B,C for scans
    }
    __syncthreads();
#pragma unroll
    for (int g = 0; g < 4; ++g) {
        const int n = g * 256 + t;
        float bb = bdt[n];
        float acc[8];
#pragma unroll
        for (int r = 0; r < 8; ++r) acc[r] = bb;
#pragma unroll
        for (int k = 0; k < DTRANK; ++k) {
            float w = WdtT[k * DINNER + n];     // coalesced, L2-resident
#pragma unroll
            for (int r = 0; r < 8; ++r) acc[r] += a[r][k] * w;
        }
#pragma unroll
        for (int r = 0; r < 8; ++r) {
            float v = acc[r];
            float sp = (v > 20.f) ? v : log1pf(expf(v));
            dtb[(size_t)(m0 + r) * DINNER + n] = f2bf(sp);
        }
    }
}

// ---------------------------------------------------------------------------
// Chunked scan pass 1 — one lane per (b,c,d), 16 states in VGPRs.
// hfinal stored bf16; dt-sums stored into dead cols 0..31 of xdbl.
__global__ __launch_bounds__(256) void scan1_kernel(
    const u16* __restrict__ ub, const float* xdbl,
    const u16* __restrict__ dtb, const float* __restrict__ A_log,
    u16* __restrict__ hfinal, float* dtsum_out)
{
    __shared__ float Bs[CLEN][16];
    const int blk  = blockIdx.x;              // b*128 + c*4 + dblk
    const int dblk = blk & 3;
    const int c    = (blk >> 2) & (CHUNKS - 1);
    const int b    = blk >> 7;
    const int d    = dblk * 256 + threadIdx.x;
    const int mbase = b * L_ + c * CLEN;

#pragma unroll
    for (int q = 0; q < 2; ++q) {
        int idx = q * 256 + threadIdx.x;
        int tt = idx >> 4, ss = idx & 15;
        Bs[tt][ss] = xdbl[(size_t)(mbase + tt) * 64 + 32 + ss];
    }
    float A[16];
    {
        float4 a4[4];
#pragma unroll
        for (int q = 0; q < 4; ++q) a4[q] = *(const float4*)&A_log[d * 16 + q * 4];
        const float* af = (const float*)a4;
#pragma unroll
        for (int s = 0; s < 16; ++s) A[s] = -__expf(af[s]);
    }
    __syncthreads();

    float h[16];
#pragma unroll
    for (int s = 0; s < 16; ++s) h[s] = 0.f;
    float dts = 0.f;

    for (int t0 = 0; t0 < CLEN; t0 += 8) {
        float dt8[8], u8[8];
#pragma unroll
        for (int j = 0; j < 8; ++j) {
            int m = mbase + t0 + j;
            dt8[j] = bf2f(dtb[(size_t)m * DINNER + d]);
            u8[j]  = bf2f(ub [(size_t)m * DINNER + d]);
        }
#pragma unroll
        for (int j = 0; j < 8; ++j) {
            float dtv = dt8[j], dtu = dtv * u8[j];
            dts += dtv;
            float Bt[16];
#pragma unroll
            for (int q = 0; q < 4; ++q)
                *(float4*)&Bt[q*4] = *(const float4*)&Bs[t0 + j][q*4];
#pragma unroll
            for (int s = 0; s < 16; ++s) {
                float dA = __expf(dtv * A[s]);
                h[s] = dA * h[s] + dtu * Bt[s];
            }
        }
    }
    size_t base = ((size_t)(b * CHUNKS + c) * DINNER + d) * 16;
    s16x8 p0, p1;
#pragma unroll
    for (int s = 0; s < 8; ++s) { p0[s] = (short)f2bf(h[s]); p1[s] = (short)f2bf(h[s+8]); }
    *(s16x8*)&hfinal[base]     = p0;
    *(s16x8*)&hfinal[base + 8] = p1;
    int i = (b * CHUNKS + c) * DINNER + d;
    dtsum_out[(i >> 5) * 64 + (i & 31)] = dts;
}

// Pass 2: sequential chunk fix-up (bf16 states, fp32 math).
__global__ __launch_bounds__(256) void scan2_kernel(
    u16* __restrict__ hfinal, const float* __restrict__ dtsum,
    const float* __restrict__ A_log)
{
    int t = blockIdx.x * 256 + threadIdx.x;   // 65536 = B_*DINNER*DSTATE
    int s = t & 15, d = (t >> 4) & (DINNER - 1), b = t >> 14;
    float As = -__expf(A_log[d * DSTATE + s]);
    float h = 0.f;
    for (int c0 = 0; c0 < CHUNKS; c0 += 8) {
        float hf8[8], dts8[8];
#pragma unroll
        for (int j = 0; j < 8; ++j) {
            int c = c0 + j;
            int i = (b * CHUNKS + c) * DINNER + d;
            dts8[j] = dtsum[(i >> 5) * 64 + (i & 31)];
            hf8[j]  = bf2f(hfinal[((size_t)i) * 16 + s]);
        }
#pragma unroll
        for (int j = 0; j < 8; ++j) {
            int c = c0 + j;
            size_t idx = ((size_t)((b * CHUNKS + c) * DINNER + d)) * 16 + s;
            hfinal[idx] = f2bf(h);
            h = __expf(As * dts8[j]) * h + hf8[j];
        }
    }
}

// Pass 3: seeded local scan; y = (C.h + u*D)*sz, written bf16.
__global__ __launch_bounds__(256) void scan3_kernel(
    const u16* __restrict__ szb, const u16* __restrict__ ub,
    const float* xdbl, const u16* __restrict__ dtb,
    const float* __restrict__ A_log, const float* __restrict__ Dp,
    const u16* __restrict__ hstart, u16* __restrict__ yb)
{
    __shared__ float Bs[CLEN][16];
    __shared__ float Cs[CLEN][16];
    const int blk  = blockIdx.x;
    const int dblk = blk & 3;
    const int c    = (blk >> 2) & (CHUNKS - 1);
    const int b    = blk >> 7;
    const int d    = dblk * 256 + threadIdx.x;
    const int mbase = b * L_ + c * CLEN;

#pragma unroll
    for (int q = 0; q < 2; ++q) {
        int idx = q * 256 + threadIdx.x;
        int tt = idx >> 4, ss = idx & 15;
        Bs[tt][ss] = xdbl[(size_t)(mbase + tt) * 64 + 32 + ss];
        Cs[tt][ss] = xdbl[(size_t)(mbase + tt) * 64 + 48 + ss];
    }
    float A[16];
    {
        float4 a4[4];
#pragma unroll
        for (int q = 0; q < 4; ++q) a4[q] = *(const float4*)&A_log[d * 16 + q * 4];
        const float* af = (const float*)a4;
#pragma unroll
        for (int s = 0; s < 16; ++s) A[s] = -__expf(af[s]);
    }
    const float Dval = Dp[d];

    float h[16];
    {
        size_t base = ((size_t)(b * CHUNKS + c) * DINNER + d) * 16;
        s16x8 p0 = *(const s16x8*)&hstart[base];
        s16x8 p1 = *(const s16x8*)&hstart[base + 8];
#pragma unroll
        for (int s = 0; s < 8; ++s) { h[s] = bf2f((u16)p0[s]); h[s+8] = bf2f((u16)p1[s]); }
    }
    __syncthreads();

    for (int t0 = 0; t0 < CLEN; t0 += 8) {
        float dt8[8], u8[8], sz8[8];
#pragma unroll
        for (int j = 0; j < 8; ++j) {
            int m = mbase + t0 + j;
            dt8[j] = bf2f(dtb[(size_t)m * DINNER + d]);
            u8[j]  = bf2f(ub [(size_t)m * DINNER + d]);
            sz8[j] = bf2f(szb[(size_t)m * DINNER + d]);
        }
#pragma unroll
        for (int j = 0; j < 8; ++j) {
            float dtv = dt8[j], dtu = dtv * u8[j];
            float Bt[16], Ct[16];
#pragma unroll
            for (int q = 0; q < 4; ++q) {
                *(float4*)&Bt[q*4] = *(const float4*)&Bs[t0 + j][q*4];
                *(float4*)&Ct[q*4] = *(const float4*)&Cs[t0 + j][q*4];
            }
            float yv = 0.f;
#pragma unroll
            for (int s = 0; s < 16; ++s) {
                float dA = __expf(dtv * A[s]);
                h[s] = dA * h[s] + dtu * Bt[s];
                yv += h[s] * Ct[s];
            }
            int m = mbase + t0 + j;
            yb[(size_t)m * DINNER + d] = f2bf((yv + u8[j] * Dval) * sz8[j]);
        }
    }
}

// ---------------------------------------------------------------------------
// Final LayerNorm over DMODEL=512, reading bf16 h.
__global__ __launch_bounds__(256) void ln_kernel(
    const u16* __restrict__ hb, const float* __restrict__ g,
    const float* __restrict__ bta, float* __restrict__ out)
{
    int m = blockIdx.x;
    size_t base = (size_t)m * DMODEL;
    int t = threadIdx.x;
    float v0 = bf2f(hb[base + t]);
    float v1 = bf2f(hb[base + t + 256]);
    float sum = v0 + v1, sq = v0*v0 + v1*v1;
#pragma unroll
    for (int off = 32; off; off >>= 1) {
        sum += __shfl_down(sum, off);
        sq  += __shfl_down(sq,  off);
    }
    __shared__ float ls[4], lq[4];
    int w = t >> 6;
    if ((t & 63) == 0) { ls[w] = sum; lq[w] = sq; }
    __syncthreads();
    sum = ls[0] + ls[1] + ls[2] + ls[3];
    sq  = lq[0] + lq[1] + lq[2] + lq[3];
    float mu  = sum * (1.f / DMODEL);
    float var = sq * (1.f / DMODEL) - mu * mu;
    float rs  = rsqrtf(var + 1e-5f);
    out[base + t]       = (v0 - mu) * rs * g[t]       + bta[t];
    out[base + t + 256] = (v1 - mu) * rs * g[t + 256] + bta[t + 256];
}

// ---------------------------------------------------------------------------
extern "C" void kernel_launch(void* const* d_in, const int* in_sizes, int n_in,
                              void* d_out, int out_size, void* d_ws, size_t ws_size,
                              hipStream_t stream)
{
    const float* x      = (const float*)d_in[0];
    const float* in_w   = (const float*)d_in[1];
    const float* in_b   = (const float*)d_in[2];
    const float* W_xz   = (const float*)d_in[3];
    const float* conv_w = (const float*)d_in[4];
    const float* conv_b = (const float*)d_in[5];
    const float* W_xp   = (const float*)d_in[6];
    const float* W_dt   = (const float*)d_in[7];
    const float* b_dt   = (const float*)d_in[8];
    const float* A_log  = (const float*)d_in[9];
    const float* D_par  = (const float*)d_in[10];
    const float* W_out  = (const float*)d_in[11];
    const float* ln_g   = (const float*)d_in[12];
    const float* ln_b   = (const float*)d_in[13];
    float* out = (float*)d_out;

    // Workspace layout (floats), total ~16.4 M floats = 65.5 MB.
    float* ws      = (float*)d_ws;
    float* hbF     = ws;                    // 1 M  : hb bf16 (2M u16)
    float* hfinF   = hbF    + 1048576;      // 1 M  : hfinal/hstart bf16 (2M u16)
    float* xcbF    = hfinF  + 1048576;      // 2 M  : xc bf16
    float* szbF    = xcbF   + 2097152;      // 2 M  : silu(z) bf16
    float* ubF     = szbF   + 2097152;      // 2 M  : u bf16
    float* xdbl    = ubF    + 2097152;      // 256 K: fp32 (B/C cols + dtsum in cols 0..31)
    float* dtbF    = xdbl   + 262144;       // 2 M  : dt bf16
    float* ybF     = dtbF   + 2097152;      // 2 M  : y bf16
    float* xpart   = ybF    + 2097152;      // 1 M  : x-proj K-split partials (4 x 256K)
    float* wxzF    = xpart  + 1048576;      // 2 M  : Wxz bf16, all layers
    float* woutF   = wxzF   + 2097152;      // 1 M  : Wout bf16, all layers
    float* wdtT    = woutF  + 1048576;      // 128 K: WdtT fp32, all layers

    u16* hb     = (u16*)hbF;
    u16* hfinal = (u16*)hfinF;
    u16* xcb  = (u16*)xcbF;
    u16* szb  = (u16*)szbF;
    u16* ub   = (u16*)ubF;
    u16* dtb  = (u16*)dtbF;
    u16* yb   = (u16*)ybF;
    u16* wxzb  = (u16*)wxzF;
    u16* woutb = (u16*)woutF;

    // One-time weight prep: bf16 GEMM weights + transposed Wdt.
    wconv_kernel<<<(DEPTH_*2048*DMODEL/8)/256, 256, 0, stream>>>(W_xz, wxzb);
    wconv_kernel<<<(DEPTH_*DMODEL*DINNER/8)/256, 256, 0, stream>>>(W_out, woutb);
    wdtT_kernel<<<(DEPTH_*DINNER*DTRANK)/256, 256, 0, stream>>>(W_dt, wdtT);

    in_proj_kernel<<<MTOT*DMODEL/256, 256, 0, stream>>>(x, in_w, in_b, hb);

    for (int layer = 0; layer < DEPTH_; ++layer) {
        const float* cw    = conv_w + (size_t)layer * DINNER * DCONV;
        const float* cb    = conv_b + (size_t)layer * DINNER;
        const float* Wxp   = W_xp   + (size_t)layer * 64 * DINNER;
        const float* wdtTL = wdtT   + (size_t)layer * DTRANK * DINNER;
        const float* bdt   = b_dt   + (size_t)layer * DINNER;
        const float* Alog  = A_log  + (size_t)layer * DINNER * DSTATE;
        const float* Dp    = D_par  + (size_t)layer * DINNER;
        const u16* wxzL    = wxzb  + (size_t)layer * 2048 * DMODEL;
        const u16* woutL   = woutb + (size_t)layer * DMODEL * DINNER;

        // xz GEMM (K=512), fused epilogue: bf16 xc + bf16 silu(z)
        gemm_bf16<128,128,1><<<dim3(2048/128, MTOT/128), 256, 0, stream>>>(
            hb, DMODEL, wxzL, DMODEL, xcb, szb, 0, DMODEL);
        // u = silu(conv(xc) + cb)
        conv_silu_kernel<<<MTOT*DINNER/2/256, 256, 0, stream>>>(xcb, cw, cb, ub);
        // x-proj K-split x4 partials
        xp_kernel<<<dim3(4, MTOT/16), 256, 0, stream>>>(ub, Wxp, xpart);
        // fused partial-sum + dt GEMM (coalesced WdtT) + softplus
        dtsum_kernel<<<MTOT/8, 256, 0, stream>>>(xpart, wdtTL, bdt, xdbl, dtb);
        // chunked selective scan (bf16 chunk states)
        scan1_kernel<<<B_*CHUNKS*(DINNER/256), 256, 0, stream>>>(ub, xdbl, dtb, Alog, hfinal, xdbl);
        scan2_kernel<<<(B_*DINNER*DSTATE)/256, 256, 0, stream>>>(hfinal, xdbl, Alog);
        scan3_kernel<<<B_*CHUNKS*(DINNER/256), 256, 0, stream>>>(szb, ub, xdbl, dtb, Alog, Dp, hfinal, yb);
        // h = y @ Wout^T (K=1024), 64x64 tile, direct bf16 epilogue
        gemm_bf16<64,64,2><<<dim3(DMODEL/64, MTOT/64), 256, 0, stream>>>(
            yb, DINNER, woutL, DINNER, hb, nullptr, DMODEL, DINNER);
    }

    ln_kernel<<<MTOT, 256, 0, stream>>>(hb, ln_g, ln_b, out);
}